// Round 6
// baseline (185.541 us; speedup 1.0000x reference)
//
#include <hip/hip_runtime.h>
#include <hip/hip_cooperative_groups.h>

namespace cg = cooperative_groups;

// B=8, N=256, M=16, D=256
// loss = sum_rows logsumexp_k(S) - sum S_self, S = w*<e,c_k>+b, LOO diagonal
constexpr int B = 8, N = 256, M = 16, D = 256;

typedef short bf16x8 __attribute__((ext_vector_type(8)));
typedef float f32x4 __attribute__((ext_vector_type(4)));

__device__ __forceinline__ unsigned short f2bf(float x) {
  unsigned u = __float_as_uint(x);
  u = (u + 0x7FFFu + ((u >> 16) & 1u)) >> 16;  // RNE
  return (unsigned short)u;
}
__device__ __forceinline__ uint4 packbf8(const float* f) {
  uint4 u;
  u.x = (unsigned)f2bf(f[0]) | ((unsigned)f2bf(f[1]) << 16);
  u.y = (unsigned)f2bf(f[2]) | ((unsigned)f2bf(f[3]) << 16);
  u.z = (unsigned)f2bf(f[4]) | ((unsigned)f2bf(f[5]) << 16);
  u.w = (unsigned)f2bf(f[6]) | ((unsigned)f2bf(f[7]) << 16);
  return u;
}

// ws: Cbf [0,1MB): B-frags uint4[(b*8+kc)*16+nt][lane]; lane l = col n=nt*16+(l&15),
//     dims kc*32+(l>>4)*8..+7 of the centroid matrix.

// ============ FUSED (cooperative, grid=256 -> 1 block/CU guaranteed) ============
// blk = b*32+sp handles 8 row-tiles (128 rows). Waves (h=row-half, c=col-half):
// wave h owns local tiles lt in {h*2, h*2+1, h*2+4, h*2+5} (t4=0..3), cols c*128..+127.
__global__ __launch_bounds__(256, 1) void k_fused(const float* __restrict__ e,
                                                  uint4* __restrict__ Cbf,
                                                  const float* __restrict__ wp,
                                                  const float* __restrict__ bp,
                                                  float* __restrict__ out) {
  const int blk = blockIdx.x;  // b*32 + sp
  const int b = blk >> 5, sp = blk & 31;
  const int tid = threadIdx.x;
  const int wid = tid >> 6, lane = tid & 63;
  const int h = wid >> 1, c = wid & 1;
  const int q = lane >> 4, m = lane & 15;

  if (blk == 0 && tid == 0) out[0] = 0.f;  // d_out re-poisoned each launch

  // ---- phase 1: E -> register A-frags, centroids -> Cbf, fp32 sqnorm ----
  uint4 a_bf[4][8];
  float sqp[4];
#pragma unroll
  for (int t4 = 0; t4 < 4; ++t4) {
    const int st = t4 >> 1, rt = t4 & 1;
    const int lt = st * 4 + h * 2 + rt;      // local row-tile 0..7
    const int jr = sp * 8 + lt;              // global row-tile == its group/column
    const float* rbase = e + ((size_t)(b * N + jr) * M + m) * D + q * 8;
    float sq = 0.f;
#pragma unroll
    for (int kc = 0; kc < 8; ++kc) {
      const float4 lo = *(const float4*)(rbase + kc * 32);
      const float4 hi = *(const float4*)(rbase + kc * 32 + 4);
      float f[8] = {lo.x, lo.y, lo.z, lo.w, hi.x, hi.y, hi.z, hi.w};
#pragma unroll
      for (int x = 0; x < 8; ++x) sq = fmaf(f[x], f[x], sq);
      a_bf[t4][kc] = packbf8(f);
      float cv[8];
#pragma unroll
      for (int x = 0; x < 8; ++x) cv[x] = f[x];
#pragma unroll
      for (int mk = 1; mk < 16; mk <<= 1)
#pragma unroll
        for (int x = 0; x < 8; ++x) cv[x] += __shfl_xor(cv[x], mk, 64);
      if (m == (jr & 15)) {  // writer lane l == q*16+(jr&15): the B-frag slot
        float cs[8];
#pragma unroll
        for (int x = 0; x < 8; ++x) cs[x] = cv[x] * (1.f / 16.f);
        Cbf[((size_t)(b * 8 + kc) * 16 + (jr >> 4)) * 64 + q * 16 + (jr & 15)] =
            packbf8(cs);
      }
    }
    sq += __shfl_xor(sq, 16, 64);
    sq += __shfl_xor(sq, 32, 64);
    sqp[t4] = sq;
  }
  float sqv[4][4];  // C-layout rows q*4+reg
#pragma unroll
  for (int t4 = 0; t4 < 4; ++t4)
#pragma unroll
    for (int reg = 0; reg < 4; ++reg) sqv[t4][reg] = __shfl(sqp[t4], q * 4 + reg, 64);

  __threadfence();
  cg::this_grid().sync();

  // ---- phase 2: MFMA GEMM, A from registers, B from Cbf (L2) ----
  const uint4* Bb = Cbf + (size_t)(b * 128 + c * 8) * 64 + lane;
  f32x4 acc[4][8];
#pragma unroll
  for (int t4 = 0; t4 < 4; ++t4)
#pragma unroll
    for (int nt = 0; nt < 8; ++nt) acc[t4][nt] = (f32x4)0.f;

#pragma unroll
  for (int kc = 0; kc < 8; ++kc) {
    uint4 bfr[8];
#pragma unroll
    for (int nt = 0; nt < 8; ++nt) bfr[nt] = Bb[(kc * 16 + nt) * 64];
#pragma unroll
    for (int nt = 0; nt < 8; ++nt) {
      const bf16x8 bv = __builtin_bit_cast(bf16x8, bfr[nt]);
#pragma unroll
      for (int t4 = 0; t4 < 4; ++t4)
        acc[t4][nt] = __builtin_amdgcn_mfma_f32_16x16x32_bf16(
            __builtin_bit_cast(bf16x8, a_bf[t4][kc]), bv, acc[t4][nt], 0, 0, 0);
    }
  }

  // ---- epilogue ----
  const float w = *wp, bias = *bp;
  __shared__ float lmx[2][128];
  __shared__ float lsm[2][128];
  __shared__ float bred[4];
  float ssum = 0.f;

#pragma unroll
  for (int t4 = 0; t4 < 4; ++t4) {
    const int lt = (t4 >> 1) * 4 + h * 2 + (t4 & 1);
    const int jr = sp * 8 + lt;
    const bool own = (c == (jr >> 7)) && (m == (jr & 15));
    const int ntd = (jr >> 4) & 7;
#pragma unroll
    for (int nt = 0; nt < 8; ++nt)
#pragma unroll
      for (int reg = 0; reg < 4; ++reg) {
        const float raw = acc[t4][nt][reg];
        float sv = fmaf(w, raw, bias);
        if (own && nt == ntd) {  // predicated, no dynamic reg indexing
          sv = fmaf(w * (1.f / 15.f), 16.f * raw - sqv[t4][reg], bias);
          ssum += sv;
        }
        acc[t4][nt][reg] = sv;
      }
#pragma unroll
    for (int reg = 0; reg < 4; ++reg) {
      float mx = acc[t4][0][reg];
#pragma unroll
      for (int nt = 1; nt < 8; ++nt) mx = fmaxf(mx, acc[t4][nt][reg]);
#pragma unroll
      for (int mk = 1; mk < 16; mk <<= 1) mx = fmaxf(mx, __shfl_xor(mx, mk, 64));
      if (m == 0) lmx[c][lt * 16 + q * 4 + reg] = mx;
    }
  }
  __syncthreads();

#pragma unroll
  for (int t4 = 0; t4 < 4; ++t4) {
    const int lt = (t4 >> 1) * 4 + h * 2 + (t4 & 1);
#pragma unroll
    for (int reg = 0; reg < 4; ++reg) {
      const int Rl = lt * 16 + q * 4 + reg;
      const float mx = fmaxf(lmx[0][Rl], lmx[1][Rl]);
      float se = 0.f;
#pragma unroll
      for (int nt = 0; nt < 8; ++nt) se += __expf(acc[t4][nt][reg] - mx);
#pragma unroll
      for (int mk = 1; mk < 16; mk <<= 1) se += __shfl_xor(se, mk, 64);
      if (m == 0) lsm[c][Rl] = se;
    }
  }
  __syncthreads();

  float part = -ssum;
  if (c == 0 && m == 0) {
#pragma unroll
    for (int t4 = 0; t4 < 4; ++t4) {
      const int lt = (t4 >> 1) * 4 + h * 2 + (t4 & 1);
#pragma unroll
      for (int reg = 0; reg < 4; ++reg) {
        const int Rl = lt * 16 + q * 4 + reg;
        const float mx = fmaxf(lmx[0][Rl], lmx[1][Rl]);
        part += mx + __logf(lsm[0][Rl] + lsm[1][Rl]);
      }
    }
  }
#pragma unroll
  for (int mk = 1; mk < 64; mk <<= 1) part += __shfl_xor(part, mk, 64);
  if (lane == 0) bred[wid] = part;
  __syncthreads();
  if (tid == 0) atomicAdd(out, bred[0] + bred[1] + bred[2] + bred[3]);
}

// ============ FALLBACK (proven R4 two-kernel path) ============
__global__ __launch_bounds__(256) void k_prep(const float* __restrict__ e,
                                              uint4* __restrict__ Cbf,
                                              float* __restrict__ out) {
  const int blk = blockIdx.x;  // b*256 + j
  const int b = blk >> 8, j = blk & 255;
  const int t = threadIdx.x;
  const float* base = e + (size_t)blk * (M * D);
  float s = 0.f;
#pragma unroll
  for (int i = 0; i < M; ++i) s += base[i * D + t];
  __shared__ float cl[D];
  cl[t] = s * (1.f / 16.f);
  __syncthreads();
  if (t < 32) {
    const int kc = t >> 2, qq = t & 3;
    float f[8];
#pragma unroll
    for (int x = 0; x < 8; ++x) f[x] = cl[kc * 32 + qq * 8 + x];
    Cbf[(size_t)((b * 8 + kc) * 16 + (j >> 4)) * 64 + qq * 16 + (j & 15)] = packbf8(f);
  }
  if (blk == 0 && t == 0) out[0] = 0.f;
}

__global__ __launch_bounds__(256) void k_gemm(const float* __restrict__ e,
                                              const uint4* __restrict__ Cbf,
                                              const float* __restrict__ wp,
                                              const float* __restrict__ bp,
                                              float* __restrict__ out) {
  const int blk = blockIdx.x;  // b*64 + strip
  const int b = blk >> 6, strip = blk & 63;
  const int tid = threadIdx.x;
  const int wid = tid >> 6, lane = tid & 63;
  const int h = wid >> 1, c = wid & 1;
  const int q = lane >> 4, m = lane & 15;

  const float* Abase =
      e + (size_t)b * (N * M * D) + (size_t)((strip * 4 + h * 2) * 16 + m) * D + q * 8;
  const uint4* Bb = Cbf + (size_t)(b * 128 + c * 8) * 64 + lane;

  f32x4 acc[2][8];
#pragma unroll
  for (int rt = 0; rt < 2; ++rt)
#pragma unroll
    for (int nt = 0; nt < 8; ++nt) acc[rt][nt] = (f32x4)0.f;
  float sqp[2] = {0.f, 0.f};

#pragma unroll 1
  for (int kc = 0; kc < 8; ++kc) {
    float fa[2][8];
#pragma unroll
    for (int rt = 0; rt < 2; ++rt) {
      const float4 lo = *(const float4*)(Abase + (size_t)rt * 16 * D + kc * 32);
      const float4 hi = *(const float4*)(Abase + (size_t)rt * 16 * D + kc * 32 + 4);
      fa[rt][0] = lo.x; fa[rt][1] = lo.y; fa[rt][2] = lo.z; fa[rt][3] = lo.w;
      fa[rt][4] = hi.x; fa[rt][5] = hi.y; fa[rt][6] = hi.z; fa[rt][7] = hi.w;
#pragma unroll
      for (int x = 0; x < 8; ++x) sqp[rt] = fmaf(fa[rt][x], fa[rt][x], sqp[rt]);
    }
    uint4 a0 = packbf8(fa[0]);
    uint4 a1 = packbf8(fa[1]);
    uint4 bfr[8];
#pragma unroll
    for (int nt = 0; nt < 8; ++nt) bfr[nt] = Bb[(kc * 16 + nt) * 64];
    bf16x8 av0 = __builtin_bit_cast(bf16x8, a0);
    bf16x8 av1 = __builtin_bit_cast(bf16x8, a1);
#pragma unroll
    for (int nt = 0; nt < 8; ++nt) {
      bf16x8 bv = __builtin_bit_cast(bf16x8, bfr[nt]);
      acc[0][nt] = __builtin_amdgcn_mfma_f32_16x16x32_bf16(av0, bv, acc[0][nt], 0, 0, 0);
      acc[1][nt] = __builtin_amdgcn_mfma_f32_16x16x32_bf16(av1, bv, acc[1][nt], 0, 0, 0);
    }
  }

#pragma unroll
  for (int rt = 0; rt < 2; ++rt) {
    sqp[rt] += __shfl_xor(sqp[rt], 16, 64);
    sqp[rt] += __shfl_xor(sqp[rt], 32, 64);
  }
  float sqv[2][4];
#pragma unroll
  for (int rt = 0; rt < 2; ++rt)
#pragma unroll
    for (int reg = 0; reg < 4; ++reg) sqv[rt][reg] = __shfl(sqp[rt], q * 4 + reg, 64);

  const float w = *wp, bias = *bp;
  __shared__ float lmx[2][64];
  __shared__ float lsm[2][64];
  __shared__ float bred[4];
  float ssum = 0.f;

#pragma unroll
  for (int rt = 0; rt < 2; ++rt) {
    const int jr = strip * 4 + h * 2 + rt;
    const bool own = (c == (jr >> 7)) && (m == (jr & 15));
    const int ntd = (jr >> 4) & 7;
#pragma unroll
    for (int nt = 0; nt < 8; ++nt)
#pragma unroll
      for (int reg = 0; reg < 4; ++reg) {
        const float raw = acc[rt][nt][reg];
        float sv = fmaf(w, raw, bias);
        if (own && nt == ntd) {
          sv = fmaf(w * (1.f / 15.f), 16.f * raw - sqv[rt][reg], bias);
          ssum += sv;
        }
        acc[rt][nt][reg] = sv;
      }
#pragma unroll
    for (int reg = 0; reg < 4; ++reg) {
      float mx = acc[rt][0][reg];
#pragma unroll
      for (int nt = 1; nt < 8; ++nt) mx = fmaxf(mx, acc[rt][nt][reg]);
#pragma unroll
      for (int mk = 1; mk < 16; mk <<= 1) mx = fmaxf(mx, __shfl_xor(mx, mk, 64));
      if (m == 0) lmx[c][(h * 2 + rt) * 16 + q * 4 + reg] = mx;
    }
  }
  __syncthreads();

#pragma unroll
  for (int rt = 0; rt < 2; ++rt)
#pragma unroll
    for (int reg = 0; reg < 4; ++reg) {
      const int Rl = (h * 2 + rt) * 16 + q * 4 + reg;
      const float mx = fmaxf(lmx[0][Rl], lmx[1][Rl]);
      float se = 0.f;
#pragma unroll
      for (int nt = 0; nt < 8; ++nt) se += __expf(acc[rt][nt][reg] - mx);
#pragma unroll
      for (int mk = 1; mk < 16; mk <<= 1) se += __shfl_xor(se, mk, 64);
      if (m == 0) lsm[c][Rl] = se;
    }
  __syncthreads();

  float part = -ssum;
  if (c == 0 && m == 0) {
#pragma unroll
    for (int rt = 0; rt < 2; ++rt)
#pragma unroll
      for (int reg = 0; reg < 4; ++reg) {
        const int Rl = (h * 2 + rt) * 16 + q * 4 + reg;
        const float mx = fmaxf(lmx[0][Rl], lmx[1][Rl]);
        part += mx + __logf(lsm[0][Rl] + lsm[1][Rl]);
      }
  }
#pragma unroll
  for (int mk = 1; mk < 64; mk <<= 1) part += __shfl_xor(part, mk, 64);
  if (lane == 0) bred[wid] = part;
  __syncthreads();
  if (tid == 0) atomicAdd(out, bred[0] + bred[1] + bred[2] + bred[3]);
}

extern "C" void kernel_launch(void* const* d_in, const int* in_sizes, int n_in,
                              void* d_out, int out_size, void* d_ws, size_t ws_size,
                              hipStream_t stream) {
  const float* e = (const float*)d_in[0];
  const float* wp = (const float*)d_in[1];
  const float* bp = (const float*)d_in[2];
  float* out = (float*)d_out;
  uint4* Cbf = (uint4*)d_ws;  // 1 MB B-fragment centroids

  void* args[] = {(void*)&e, (void*)&Cbf, (void*)&wp, (void*)&bp, (void*)&out};
  hipError_t rc = hipLaunchCooperativeKernel((const void*)k_fused, dim3(B * 32),
                                             dim3(256), args, 0, stream);
  if (rc != hipSuccess) {
    // deterministic fallback: proven two-kernel path (same math, same Cbf layout)
    k_prep<<<B * N, 256, 0, stream>>>(e, Cbf, out);
    k_gemm<<<B * 64, 256, 0, stream>>>(e, Cbf, wp, bp, out);
  }
}

// Round 7
// 100.522 us; speedup vs baseline: 1.8458x; 1.8458x over previous
//
#include <hip/hip_runtime.h>

// B=8, N=256, M=16, D=256
// loss = sum_rows logsumexp_k(S) - sum S_self, S = w*<e,c_k>+b, LOO diagonal
constexpr int B = 8, N = 256, M = 16, D = 256;
constexpr int LTS = 260;  // LDS row stride (floats), 16B-aligned

typedef short bf16x8 __attribute__((ext_vector_type(8)));
typedef float f32x4 __attribute__((ext_vector_type(4)));

__device__ __forceinline__ unsigned short f2bf(float x) {
  unsigned u = __float_as_uint(x);
  u = (u + 0x7FFFu + ((u >> 16) & 1u)) >> 16;  // RNE
  return (unsigned short)u;
}
__device__ __forceinline__ uint4 packbf8(const float* f) {
  uint4 u;
  u.x = (unsigned)f2bf(f[0]) | ((unsigned)f2bf(f[1]) << 16);
  u.y = (unsigned)f2bf(f[2]) | ((unsigned)f2bf(f[3]) << 16);
  u.z = (unsigned)f2bf(f[4]) | ((unsigned)f2bf(f[5]) << 16);
  u.w = (unsigned)f2bf(f[6]) | ((unsigned)f2bf(f[7]) << 16);
  return u;
}

// ws layout:
//  EbfA [0,16MB):   A-frags uint4[(b*256+j)*8+kc][lane]; lane l = row m=l&15,
//                   dims kc*32+(l>>4)*8..+7
//  Cbf [16,17MB):   B-frags uint4[(b*8+kc)*16+nt][lane]; lane l = col n=nt*16+(l&15),
//                   dims kc*32+(l>>4)*8..+7
//  SQ  [17MB,+128KB): fp32 ||e_row||^2, [blk*16 + i]

// One block per (b,j): read tile once, emit A-frags + centroid B-frags + sqnorm.
__global__ __launch_bounds__(256) void k_prep(const float* __restrict__ e,
                                              uint4* __restrict__ EbfA,
                                              uint4* __restrict__ Cbf,
                                              float* __restrict__ SQ,
                                              float* __restrict__ out) {
  const int blk = blockIdx.x;  // b*256 + j
  const int b = blk >> 8, j = blk & 255;
  const int t = threadIdx.x;
  const int w = t >> 6, l = t & 63;
  const int q = l >> 4, m = l & 15;
  const float* base = e + (size_t)blk * (M * D);

  __shared__ float lt[M * LTS];  // fp32 tile, stride 260
  __shared__ float cl[D];
  __shared__ float sqred[4][16];

  // pass 1: coalesced load (1KB/instr), centroid column-sum in registers
  float ev[M];
  float cs = 0.f;
#pragma unroll
  for (int i = 0; i < M; ++i) {
    ev[i] = base[i * D + t];
    cs += ev[i];
  }
#pragma unroll
  for (int i = 0; i < M; ++i) lt[i * LTS + t] = ev[i];
  cl[t] = cs * (1.f / 16.f);
  __syncthreads();

  // pass 2: wave w -> kc {2w, 2w+1}; lane (q,m) reads row m dims kc*32+q*8..+7
  float sq = 0.f;
#pragma unroll
  for (int kk = 0; kk < 2; ++kk) {
    const int kc = 2 * w + kk;
    const float* src = &lt[m * LTS + kc * 32 + q * 8];
    float f[8];
#pragma unroll
    for (int x = 0; x < 8; ++x) f[x] = src[x];
#pragma unroll
    for (int x = 0; x < 8; ++x) sq = fmaf(f[x], f[x], sq);
    EbfA[(size_t)(blk * 8 + kc) * 64 + l] = packbf8(f);  // coalesced 16B/lane
  }
  sq += __shfl_xor(sq, 16, 64);
  sq += __shfl_xor(sq, 32, 64);
  if (q == 0) sqred[w][m] = sq;

  // centroid -> B-frag slots (32 threads, 8 dims each)
  if (t < 32) {
    const int kc = t >> 2, qq = t & 3;
    float f[8];
#pragma unroll
    for (int x = 0; x < 8; ++x) f[x] = cl[kc * 32 + qq * 8 + x];
    Cbf[(size_t)((b * 8 + kc) * 16 + (j >> 4)) * 64 + qq * 16 + (j & 15)] = packbf8(f);
  }
  __syncthreads();
  if (t < 16) SQ[blk * 16 + t] = sqred[0][t] + sqred[1][t] + sqred[2][t] + sqred[3][t];
  if (blk == 0 && t == 0) out[0] = 0.f;  // d_out re-poisoned each launch
}

// One block per (b, 64-row strip). 4 waves 2x2: h=row-half (2 tiles), c=col-half (8 nt).
// Pure MFMA: A-frags pre-swizzled bf16 (prefetched), B from Cbf, sqnorm precomputed.
__global__ __launch_bounds__(256) void k_gemm(const uint4* __restrict__ EbfA,
                                              const uint4* __restrict__ Cbf,
                                              const float* __restrict__ SQ,
                                              const float* __restrict__ wp,
                                              const float* __restrict__ bp,
                                              float* __restrict__ out) {
  const int blk = blockIdx.x;  // b*64 + strip
  const int b = blk >> 6, strip = blk & 63;
  const int tid = threadIdx.x;
  const int wid = tid >> 6, lane = tid & 63;
  const int h = wid >> 1, c = wid & 1;
  const int q = lane >> 4, m = lane & 15;
  const float w = *wp, bias = *bp;  // scalar loads issued early

  const uint4* Ab = EbfA + (size_t)((b * 256 + strip * 4 + h * 2) * 8) * 64 + lane;
  const uint4* Bb = Cbf + (size_t)(b * 128 + c * 8) * 64 + lane;

  f32x4 acc[2][8];
#pragma unroll
  for (int rt = 0; rt < 2; ++rt)
#pragma unroll
    for (int nt = 0; nt < 8; ++nt) acc[rt][nt] = (f32x4)0.f;

  uint4 aC0 = Ab[0], aC1 = Ab[8 * 64];  // kc=0 A-frags, rt=0/1
#pragma unroll 1
  for (int kc = 0; kc < 8; ++kc) {
    uint4 aN0, aN1;
    if (kc < 7) {  // prefetch next-kc A while B loads + MFMAs run
      aN0 = Ab[(kc + 1) * 64];
      aN1 = Ab[(8 + kc + 1) * 64];
    }
    uint4 bfr[8];
#pragma unroll
    for (int nt = 0; nt < 8; ++nt) bfr[nt] = Bb[(kc * 16 + nt) * 64];
    const bf16x8 av0 = __builtin_bit_cast(bf16x8, aC0);
    const bf16x8 av1 = __builtin_bit_cast(bf16x8, aC1);
#pragma unroll
    for (int nt = 0; nt < 8; ++nt) {
      const bf16x8 bv = __builtin_bit_cast(bf16x8, bfr[nt]);
      acc[0][nt] = __builtin_amdgcn_mfma_f32_16x16x32_bf16(av0, bv, acc[0][nt], 0, 0, 0);
      acc[1][nt] = __builtin_amdgcn_mfma_f32_16x16x32_bf16(av1, bv, acc[1][nt], 0, 0, 0);
    }
    if (kc < 7) { aC0 = aN0; aC1 = aN1; }
  }

  // ---- epilogue: scale, LOO diagonal, logsumexp ----
  __shared__ float lmx[2][64];
  __shared__ float lsm[2][64];
  __shared__ float bred[4];
  float ssum = 0.f;

#pragma unroll
  for (int rt = 0; rt < 2; ++rt) {
    const int jr = strip * 4 + h * 2 + rt;  // global row-tile == diag col
    const bool own = (c == (jr >> 7)) && (m == (jr & 15));
    const int ntd = (jr >> 4) & 7;
    float sqv[4];
    if (own) {
#pragma unroll
      for (int reg = 0; reg < 4; ++reg)
        sqv[reg] = SQ[b * 4096 + jr * 16 + q * 4 + reg];
    }
#pragma unroll
    for (int nt = 0; nt < 8; ++nt)
#pragma unroll
      for (int reg = 0; reg < 4; ++reg) {
        const float raw = acc[rt][nt][reg];
        float sv = fmaf(w, raw, bias);
        if (own && nt == ntd) {  // predicated, no dynamic reg indexing
          sv = fmaf(w * (1.f / 15.f), 16.f * raw - sqv[reg], bias);
          ssum += sv;
        }
        acc[rt][nt][reg] = sv;
      }
#pragma unroll
    for (int reg = 0; reg < 4; ++reg) {
      float mx = acc[rt][0][reg];
#pragma unroll
      for (int nt = 1; nt < 8; ++nt) mx = fmaxf(mx, acc[rt][nt][reg]);
#pragma unroll
      for (int mk = 1; mk < 16; mk <<= 1) mx = fmaxf(mx, __shfl_xor(mx, mk, 64));
      if (m == 0) lmx[c][(h * 2 + rt) * 16 + q * 4 + reg] = mx;
    }
  }
  __syncthreads();

#pragma unroll
  for (int rt = 0; rt < 2; ++rt)
#pragma unroll
    for (int reg = 0; reg < 4; ++reg) {
      const int Rl = (h * 2 + rt) * 16 + q * 4 + reg;
      const float mx = fmaxf(lmx[0][Rl], lmx[1][Rl]);
      float se = 0.f;
#pragma unroll
      for (int nt = 0; nt < 8; ++nt) se += __expf(acc[rt][nt][reg] - mx);
#pragma unroll
      for (int mk = 1; mk < 16; mk <<= 1) se += __shfl_xor(se, mk, 64);
      if (m == 0) lsm[c][Rl] = se;
    }
  __syncthreads();

  float part = -ssum;
  if (c == 0 && m == 0) {
#pragma unroll
    for (int rt = 0; rt < 2; ++rt)
#pragma unroll
      for (int reg = 0; reg < 4; ++reg) {
        const int Rl = (h * 2 + rt) * 16 + q * 4 + reg;
        const float mx = fmaxf(lmx[0][Rl], lmx[1][Rl]);
        part += mx + __logf(lsm[0][Rl] + lsm[1][Rl]);
      }
  }
#pragma unroll
  for (int mk = 1; mk < 64; mk <<= 1) part += __shfl_xor(part, mk, 64);
  if (lane == 0) bred[wid] = part;
  __syncthreads();
  if (tid == 0) atomicAdd(out, bred[0] + bred[1] + bred[2] + bred[3]);
}

extern "C" void kernel_launch(void* const* d_in, const int* in_sizes, int n_in,
                              void* d_out, int out_size, void* d_ws, size_t ws_size,
                              hipStream_t stream) {
  const float* e = (const float*)d_in[0];
  const float* wp = (const float*)d_in[1];
  const float* bp = (const float*)d_in[2];
  float* out = (float*)d_out;
  char* ws = (char*)d_ws;
  uint4* EbfA = (uint4*)ws;                              // 16 MB A-frags
  uint4* Cbf = (uint4*)(ws + (size_t)16 * 1024 * 1024);  // 1 MB B-frags
  float* SQ = (float*)(ws + (size_t)17 * 1024 * 1024);   // 128 KB sqnorms

  k_prep<<<B * N, 256, 0, stream>>>(e, EbfA, Cbf, SQ, out);
  k_gemm<<<B * 64, 256, 0, stream>>>(EbfA, Cbf, SQ, wp, bp, out);
}